// Round 2
// baseline (36.783 us; speedup 1.0000x reference)
//
#include <hip/hip_runtime.h>

// Problem constants
#define BB 4
#define LL 512
#define WW 256
#define EE 300
#define EP 320      // E padded to multiple of 32 (zero-filled)
#define HH 768
#define GG 1024     // B*W rows of `a`

typedef __attribute__((ext_vector_type(8))) short bf16x8;
typedef __attribute__((ext_vector_type(4))) short bf16x4;
typedef __attribute__((ext_vector_type(4))) float f32x4;

__device__ __forceinline__ short f2bf(float f) {
    union { float f; unsigned u; } v; v.f = f;
    unsigned r = (v.u + 0x7FFFu + ((v.u >> 16) & 1u)) >> 16;
    return (short)r;
}

// ---------------------------------------------------------------------------
// k0: (a) transpose+convert lin_w [300][768] f32 -> lwT [768][320] bf16
//     (zero-padded cols 300..319), via 32x32 LDS tiles (240 blocks);
//     (b) convert hidden [2048][768] f32 -> bf16 (768 blocks).
// No dependency on other kernels' outputs.
// ---------------------------------------------------------------------------
__global__ __launch_bounds__(256) void k0_prep(
    const float* __restrict__ lin_w,
    const float* __restrict__ hidden,
    short*       __restrict__ lwT,    // [768][320] bf16
    short*       __restrict__ hidb)   // [2048*768] bf16
{
    const int bid = blockIdx.x;
    const int t   = threadIdx.x;
    if (bid < 240) {
        // ---- lin_w transpose tile: e-tile = bid%10, h-tile = bid/10
        __shared__ float tile[32][33];
        const int e0 = (bid % 10) * 32;
        const int h0 = (bid / 10) * 32;
        const int c  = t & 31;        // h offset
        const int r4 = t >> 5;        // 0..7
#pragma unroll
        for (int rr = 0; rr < 4; ++rr) {
            const int r = r4 + rr * 8;          // e offset 0..31
            const int e = e0 + r;
            tile[r][c] = (e < EE) ? lin_w[(long)e * HH + h0 + c] : 0.f;
        }
        __syncthreads();
        const int hr = t >> 3;            // 0..31 (h offset)
        const int ec = (t & 7) * 4;       // e offset, 4 elems
        bf16x4 v;
#pragma unroll
        for (int j = 0; j < 4; ++j) v[j] = f2bf(tile[ec + j][hr]);
        *(bf16x4*)(&lwT[(long)(h0 + hr) * EP + e0 + ec]) = v;
    } else {
        // ---- hidden f32 -> bf16, 2048 elems per block
        const long idx = (long)(bid - 240) * 2048 + (long)t * 8;
        const float4 p0 = *(const float4*)(hidden + idx);
        const float4 p1 = *(const float4*)(hidden + idx + 4);
        bf16x8 v;
        v[0] = f2bf(p0.x); v[1] = f2bf(p0.y); v[2] = f2bf(p0.z); v[3] = f2bf(p0.w);
        v[4] = f2bf(p1.x); v[5] = f2bf(p1.y); v[6] = f2bf(p1.z); v[7] = f2bf(p1.w);
        *(bf16x8*)(hidb + idx) = v;
    }
}

// ---------------------------------------------------------------------------
// k1: a[g][h] = emb_a[word_seq[g]] @ lin_w + lin_b, bf16 out.
// 1 wave per block, tile 16m x 64n, K=300 (pad 320). No LDS, no barriers:
// A-frags = gathered f32 loads + convert; B-frags = direct 16B from lwT.
// grid (1024/16, 768/64) = (64, 12).
// ---------------------------------------------------------------------------
__global__ __launch_bounds__(64) void k1_a_gemm(
    const int*   __restrict__ word_seq,
    const float* __restrict__ emb_a,
    const float* __restrict__ lin_b,
    const short* __restrict__ lwT,
    short*       __restrict__ a_g)     // [1024][768] bf16
{
    const int lane = threadIdx.x;
    const int l15 = lane & 15, l4 = lane >> 4;
    const int m0 = blockIdx.x * 16;
    const int n0 = blockIdx.y * 64;

    const int wrow = word_seq[m0 + l15];          // this lane's fixed m-row
    const float* arow = emb_a + (long)wrow * EE;  // 16B-aligned (300*4B)

    f32x4 acc[4] = {};

#pragma unroll
    for (int e0 = 0; e0 < 288; e0 += 32) {        // 9 full iterations
        const int c = e0 + l4 * 8;                // c+8 <= 288 < 300: unguarded
        const float4 p0 = *(const float4*)(arow + c);
        const float4 p1 = *(const float4*)(arow + c + 4);
        bf16x8 af;
        af[0] = f2bf(p0.x); af[1] = f2bf(p0.y); af[2] = f2bf(p0.z); af[3] = f2bf(p0.w);
        af[4] = f2bf(p1.x); af[5] = f2bf(p1.y); af[6] = f2bf(p1.z); af[7] = f2bf(p1.w);
#pragma unroll
        for (int nf = 0; nf < 4; ++nf) {
            const bf16x8 bfv = *(const bf16x8*)(lwT + (long)(n0 + nf * 16 + l15) * EP + c);
            acc[nf] = __builtin_amdgcn_mfma_f32_16x16x32_bf16(af, bfv, acc[nf], 0, 0, 0);
        }
    }
    {   // tail e0 = 288: guard loads past E=300 (lwT side is zero-padded)
        const int c = 288 + l4 * 8;
        bf16x8 af;
#pragma unroll
        for (int j = 0; j < 8; ++j)
            af[j] = (c + j < EE) ? f2bf(arow[c + j]) : (short)0;
#pragma unroll
        for (int nf = 0; nf < 4; ++nf) {
            const bf16x8 bfv = *(const bf16x8*)(lwT + (long)(n0 + nf * 16 + l15) * EP + c);
            acc[nf] = __builtin_amdgcn_mfma_f32_16x16x32_bf16(af, bfv, acc[nf], 0, 0, 0);
        }
    }

    // epilogue: bias + bf16 store. D: col = l&15, row = (l>>4)*4 + i
#pragma unroll
    for (int nf = 0; nf < 4; ++nf) {
        const int h    = n0 + nf * 16 + l15;
        const float bv = lin_b[h];
#pragma unroll
        for (int i = 0; i < 4; ++i) {
            const int m = m0 + l4 * 4 + i;
            a_g[(long)m * HH + h] = f2bf(acc[nf][i] + bv);
        }
    }
}

// ---------------------------------------------------------------------------
// k2: per (b, 16 l-rows): u = hid_tile @ a_b^T via direct-from-global MFMA
// fragments (no operand LDS, no barriers in the K loop), then exp/bucket
// sums s[c] and fused output o = (sum_c s_c * emb_c[c]) / (sum + 1e-10).
// 256 threads = 4 waves; wave wv owns w in [wv*64, wv*64+64).
// ---------------------------------------------------------------------------
__global__ __launch_bounds__(256) void k2_attn(
    const short* __restrict__ hidb,    // [2048][768] bf16
    const int*   __restrict__ label,   // [4][512][256]
    const short* __restrict__ a_g,     // [1024][768] bf16
    const float* __restrict__ emb_c,   // [6][768]
    float*       __restrict__ out)     // [4][512][768]
{
    __shared__ float s_part[4][16][5];
    __shared__ float s_fin[16][5];
    __shared__ float invd[16];

    const int t = threadIdx.x, lane = t & 63, wv = t >> 6;
    const int l15 = lane & 15, l4 = lane >> 4;
    const int bl0 = blockIdx.x * 16;          // flat (b*512 + l) row base
    const int b   = bl0 >> 9;

    const short* hbase = hidb + (long)bl0 * HH;
    const short* abase = a_g + (long)b * WW * HH;

    f32x4 acc[4] = {};
#pragma unroll
    for (int ks = 0; ks < 24; ++ks) {
        const int k0 = ks * 32;
        const bf16x8 af = *(const bf16x8*)(hbase + (long)l15 * HH + k0 + l4 * 8);
#pragma unroll
        for (int nf = 0; nf < 4; ++nf) {
            const int w = wv * 64 + nf * 16 + l15;
            const bf16x8 bfv = *(const bf16x8*)(abase + (long)w * HH + k0 + l4 * 8);
            acc[nf] = __builtin_amdgcn_mfma_f32_16x16x32_bf16(af, bfv, acc[nf], 0, 0, 0);
        }
    }

    // ---- exp + masked label-bucket accumulation (static indexing only)
    const float inv_temper = 0.03608439182435161f;   // 1/sqrt(768)
    float s_loc[4][5];
#pragma unroll
    for (int i = 0; i < 4; ++i)
#pragma unroll
        for (int c = 0; c < 5; ++c) s_loc[i][c] = 0.f;

    const int* lab_base = label + (long)bl0 * WW;
#pragma unroll
    for (int nf = 0; nf < 4; ++nf) {
        const int w = wv * 64 + nf * 16 + l15;
#pragma unroll
        for (int i = 0; i < 4; ++i) {
            const int row = l4 * 4 + i;
            const int lv  = lab_base[row * WW + w];
            const float e = __expf(acc[nf][i] * inv_temper);
#pragma unroll
            for (int c = 1; c <= 5; ++c)
                s_loc[i][c - 1] += (lv == c) ? e : 0.f;
        }
    }
    // reduce across the 16 lanes (w-index) sharing the same l4 group
#pragma unroll
    for (int i = 0; i < 4; ++i) {
#pragma unroll
        for (int c = 0; c < 5; ++c) {
            float v = s_loc[i][c];
            v += __shfl_xor(v, 1);
            v += __shfl_xor(v, 2);
            v += __shfl_xor(v, 4);
            v += __shfl_xor(v, 8);
            s_loc[i][c] = v;
        }
    }
    if (l15 == 0) {
#pragma unroll
        for (int i = 0; i < 4; ++i)
#pragma unroll
            for (int c = 0; c < 5; ++c)
                s_part[wv][l4 * 4 + i][c] = s_loc[i][c];
    }
    __syncthreads();
    if (t < 16) {
        float den = 0.f;
#pragma unroll
        for (int c = 0; c < 5; ++c) {
            const float s = s_part[0][t][c] + s_part[1][t][c] +
                            s_part[2][t][c] + s_part[3][t][c];
            s_fin[t][c] = s;
            den += s;
        }
        invd[t] = 1.0f / (den + 1e-10f);
    }
    __syncthreads();

    // ---- fused output: o[row][h] = invd * sum_c s_c * emb_c[c][h]
    float ecv[3][5];
#pragma unroll
    for (int q = 0; q < 3; ++q)
#pragma unroll
        for (int c = 0; c < 5; ++c)
            ecv[q][c] = emb_c[(c + 1) * HH + t + q * 256];

    float* obase = out + (long)bl0 * HH;
    for (int row = 0; row < 16; ++row) {
        const float id = invd[row];
        const float s0 = s_fin[row][0], s1 = s_fin[row][1], s2 = s_fin[row][2],
                    s3 = s_fin[row][3], s4 = s_fin[row][4];
#pragma unroll
        for (int q = 0; q < 3; ++q) {
            const float v = s0 * ecv[q][0] + s1 * ecv[q][1] + s2 * ecv[q][2] +
                            s3 * ecv[q][3] + s4 * ecv[q][4];
            obase[(long)row * HH + t + q * 256] = v * id;
        }
    }
}

extern "C" void kernel_launch(void* const* d_in, const int* in_sizes, int n_in,
                              void* d_out, int out_size, void* d_ws, size_t ws_size,
                              hipStream_t stream) {
    const int*   word_seq = (const int*)  d_in[0];
    const float* hidden   = (const float*)d_in[1];
    const int*   label    = (const int*)  d_in[2];
    const float* emb_a    = (const float*)d_in[3];
    const float* lin_w    = (const float*)d_in[4];
    const float* lin_b    = (const float*)d_in[5];
    const float* emb_c    = (const float*)d_in[6];
    float* out = (float*)d_out;

    short* lwT  = (short*)d_ws;                  // 768*320  = 245760 shorts
    short* hidb = lwT + (long)HH * EP;           // 2048*768 = 1572864 shorts
    short* a_g  = hidb + (long)BB * LL * HH;     // 1024*768 shorts

    k0_prep<<<dim3(240 + 768), 256, 0, stream>>>(lin_w, hidden, lwT, hidb);
    k1_a_gemm<<<dim3(64, 12), 64, 0, stream>>>(word_seq, emb_a, lin_b, lwT, a_g);
    k2_attn<<<dim3(128), 256, 0, stream>>>(hidb, label, a_g, emb_c, out);
}